// Round 3
// baseline (1341.704 us; speedup 1.0000x reference)
//
#include <hip/hip_runtime.h>
#include <hip/hip_bf16.h>

#define FEAT 64
#define CHUNK 8192   // edges per P1/P3 chunk
#define MAX_NB 2048  // max buckets (64 nodes/bucket -> N <= 131072)

typedef __attribute__((ext_vector_type(8))) short bf16x8;
typedef __attribute__((ext_vector_type(4))) float f32x4;
typedef __attribute__((ext_vector_type(2))) float f32x2;

// ---------- bf16 helpers ----------
__device__ __forceinline__ float bflo2f(unsigned int u) {
    union { unsigned int u; float f; } v; v.u = u << 16; return v.f;
}
__device__ __forceinline__ float bfhi2f(unsigned int u) {
    union { unsigned int u; float f; } v; v.u = u & 0xffff0000u; return v.f;
}
__device__ __forceinline__ unsigned short f2bf(float f) {
    union { float f; unsigned int u; } v; v.f = f;
    unsigned int u = v.u;
    u += 0x7fffu + ((u >> 16) & 1u);   // round-to-nearest-even
    return (unsigned short)(u >> 16);
}
__device__ __forceinline__ f32x2 bfpair(unsigned int u) {
    f32x2 r; r.x = bflo2f(u & 0xffffu); r.y = bfhi2f(u); return r;
}

// ---------- 0. prep + P1 merged: role-split grid ----------
// blocks [0, pB): dtype detect + weight conversion + x conversion (as before)
// blocks [pB, pB+EC): per-chunk bucket histogram (bucket = dst >> 6)
// p1-role blocks self-detect int64 (read first 256 high words locally) -> no
// dependency on flags written by block 0.
__global__ __launch_bounds__(256) void prep_p1_kernel(
    const unsigned short* __restrict__ xh, const int* __restrict__ ei32,
    const void* __restrict__ w1a, const void* __restrict__ w1r,
    const void* __restrict__ b1,  const void* __restrict__ w2a,
    const void* __restrict__ w2r, const void* __restrict__ b2,
    const void* __restrict__ wl,  const void* __restrict__ bl,
    float* __restrict__ wbuf, unsigned short* __restrict__ Wt,
    int* __restrict__ flags, const void* __restrict__ x_in,
    unsigned short* __restrict__ x16, int n8,
    int* __restrict__ hist, int E, int N, int NB, int EC, int pB) {
    __shared__ int lh[MAX_NB];
    __shared__ int cnt_bf, cnt_nz;
    int tid = threadIdx.x;

    if (blockIdx.x >= pB) {
        // ---- P1 role: histogram of chunk c ----
        int c = blockIdx.x - pB;
        if (tid == 0) cnt_nz = 0;
        for (int i = tid; i < NB; i += 256) lh[i] = 0;
        __syncthreads();
        if (ei32[tid * 2 + 1] != 0) atomicAdd(&cnt_nz, 1);
        __syncthreads();
        int idx64 = (cnt_nz < 8) ? 1 : 0;
        long base = (long)c * CHUNK;
#pragma unroll 4
        for (int j = 0; j < CHUNK / 256; ++j) {
            long e = base + j * 256 + tid;
            if (e < E) {
                int d = idx64 ? ei32[2 * ((long)E + e)] : ei32[(long)E + e];
                if ((unsigned)d < (unsigned)N)
                    atomicAdd(&lh[d >> 6], 1);
            }
        }
        __syncthreads();
        for (int k = tid; k < NB; k += 256) hist[(long)k * EC + c] = lh[k];
        return;
    }

    // ---- prep role ----
    if (tid == 0) { cnt_bf = 0; cnt_nz = 0; }
    __syncthreads();
    unsigned short h = xh[tid * 2];
    int e = (h >> 7) & 0xFF;
    if (e >= 110 && e <= 132) atomicAdd(&cnt_bf, 1);
    if (ei32[tid * 2 + 1] != 0) atomicAdd(&cnt_nz, 1);
    __syncthreads();
    int f0 = (cnt_bf >= 128) ? 1 : 0;
    if (blockIdx.x == 0 && tid == 0) {
        flags[0] = f0;
        flags[1] = (cnt_nz < 8) ? 1 : 0;
    }
    int i = blockIdx.x * 256 + tid;
    // weights (blocks 0..65): wbuf f32 + Wt bf16-transposed
    if (i < 16642) {
        const void* src; int off;
        if      (i < 4096)  { src = w1a; off = i; }
        else if (i < 8192)  { src = w1r; off = i - 4096; }
        else if (i < 8256)  { src = b1;  off = i - 8192; }
        else if (i < 12352) { src = w2a; off = i - 8256; }
        else if (i < 16448) { src = w2r; off = i - 12352; }
        else if (i < 16512) { src = b2;  off = i - 16448; }
        else if (i < 16640) { src = wl;  off = i - 16512; }
        else                { src = bl;  off = i - 16640; }
        float v = f0 ? bflo2f(((const unsigned short*)src)[off])
                     : ((const float*)src)[off];
        wbuf[i] = v;
        unsigned short hv = f2bf(v);   // exact round-trip when input was bf16
        if (i < 4096)                      Wt[(off & 63) * 128 + (off >> 6)] = hv;
        else if (i < 8192)                 Wt[(off & 63) * 128 + 64 + (off >> 6)] = hv;
        else if (i >= 8256 && i < 12352)   Wt[8192 + (off & 63) * 128 + (off >> 6)] = hv;
        else if (i >= 12352 && i < 16448)  Wt[8192 + (off & 63) * 128 + 64 + (off >> 6)] = hv;
    }
    // x -> bf16 (fp32 path only)
    if (!f0 && i < n8) {
        float4 a = ((const float4*)x_in)[2 * i];
        float4 b = ((const float4*)x_in)[2 * i + 1];
        uint4 o;
        o.x = (unsigned int)f2bf(a.x) | ((unsigned int)f2bf(a.y) << 16);
        o.y = (unsigned int)f2bf(a.z) | ((unsigned int)f2bf(a.w) << 16);
        o.z = (unsigned int)f2bf(b.x) | ((unsigned int)f2bf(b.y) << 16);
        o.w = (unsigned int)f2bf(b.z) | ((unsigned int)f2bf(b.w) << 16);
        ((uint4*)x16)[i] = o;
    }
}

// ---------- scan: multi-block scan1 + scan3 ----------
__global__ __launch_bounds__(256) void scan1_kernel(const int* __restrict__ in,
                                                    int* __restrict__ out,
                                                    int* __restrict__ blocksum, int n) {
    int tid = threadIdx.x;
    int base = blockIdx.x * 2048 + tid * 8;
    int v[8];
    int tsum = 0;
#pragma unroll
    for (int i = 0; i < 8; ++i) {
        v[i] = (base + i < n) ? in[base + i] : 0;
        tsum += v[i];
    }
    int lane = tid & 63;
    int x = tsum;
#pragma unroll
    for (int off = 1; off < 64; off <<= 1) {
        int y = __shfl_up(x, off);
        if (lane >= off) x += y;
    }
    __shared__ int wsum[4];
    int wave = tid >> 6;
    if (lane == 63) wsum[wave] = x;
    __syncthreads();
    int woff = 0;
#pragma unroll
    for (int w = 0; w < 4; ++w) if (w < wave) woff += wsum[w];
    int run = woff + x - tsum;
#pragma unroll
    for (int i = 0; i < 8; ++i) {
        if (base + i < n) out[base + i] = run;
        run += v[i];
    }
    if (tid == 255) blocksum[blockIdx.x] = woff + x;
}

// scan3: block bb owns [bb*2048, +2048) -> uniform prefix via one LDS reduce.
__global__ __launch_bounds__(256) void scan3_kernel(int* __restrict__ out,
                                                    const int* __restrict__ blocksum, int n) {
    int bb = blockIdx.x, tid = threadIdx.x;
    __shared__ int wsum[4];
    __shared__ int spre;
    int s = 0;
    for (int b = tid; b < bb; b += 256) s += blocksum[b];
#pragma unroll
    for (int off = 32; off > 0; off >>= 1) s += __shfl_down(s, off);
    int lane = tid & 63, wave = tid >> 6;
    if (lane == 0) wsum[wave] = s;
    __syncthreads();
    if (tid == 0) spre = wsum[0] + wsum[1] + wsum[2] + wsum[3];
    __syncthreads();
    int pre = spre;
    int base = bb * 2048;
#pragma unroll
    for (int k = 0; k < 8; ++k) {
        int i = base + k * 256 + tid;
        if (i < n) out[i] += pre;
    }
}

// ---------- P3: scatter packed edges into bucket-major order ----------
// packed = src | ((dst & 63) << 20)   (requires N < 2^20)
__global__ __launch_bounds__(256) void p3_scatter_kernel(
    const int* __restrict__ ei32, const int* __restrict__ hscan,
    int* __restrict__ bkt, int E, int N, int NB, int EC,
    const int* __restrict__ flags) {
    __shared__ int lh[MAX_NB];
    int tid = threadIdx.x, c = blockIdx.x;
    for (int i = tid; i < NB; i += 256) lh[i] = 0;
    __syncthreads();
    int idx64 = flags[1];
    long base = (long)c * CHUNK;
#pragma unroll 4
    for (int j = 0; j < CHUNK / 256; ++j) {
        long e = base + j * 256 + tid;
        if (e < E) {
            int s = idx64 ? ei32[2 * e]             : ei32[e];
            int d = idx64 ? ei32[2 * ((long)E + e)] : ei32[(long)E + e];
            if ((unsigned)d < (unsigned)N) {
                if ((unsigned)s >= (unsigned)N) s = 0;   // clamp (memory safety)
                int k = d >> 6;
                int r = atomicAdd(&lh[k], 1);
                bkt[hscan[(long)k * EC + c] + r] = s | ((d & 63) << 20);
            }
        }
    }
}

// ---------- FUSED: edge-parallel aggregate (LDS f32 atomics) + MFMA GEMM ----------
// Block = bucket = 64 nodes. Reads the bucket's packed edges straight from bkt
// (coalesced, unsorted) -> no p4 kernel, no offs/cnt/srcs arrays, no per-node
// degree imbalance (E[max of 8 Poisson(16)] ~ 25 vs mean 16 was ~35% idle).
// Aacc[64][68] f32 accumulators in LDS via ds_add_f32; converted in place to
// the bf16 A_l[64][136] MFMA layout (same 272 B row stride). 17.7 KB LDS ->
// up to 8 blocks/CU. No launch-bounds min-waves (round-2 lesson: reg cap
// killed gather MLP).
__global__ __launch_bounds__(256) void sage_fused_kernel(
    const void* __restrict__ feat_raw, const unsigned short* __restrict__ feat_ws,
    const int* __restrict__ bkt, const int* __restrict__ hscan,
    const int* __restrict__ hist,
    const unsigned short* __restrict__ Wt, const float* __restrict__ bias,
    unsigned short* __restrict__ out16, int N, int NB, int EC,
    const float* __restrict__ wl, const float* __restrict__ bl,
    void* __restrict__ out_final, const int* __restrict__ flags, int sel) {

    // sel=1 (layer 1): bf16 input -> read x_in directly, else converted x16.
    // sel=0 (layer 2): feat_raw == feat_ws == h16.
    const unsigned short* feat16 =
        (sel && !flags[0]) ? feat_ws : (const unsigned short*)feat_raw;

    __shared__ float Aacc[64][68];   // f32 accum; reused as bf16 A_l[64][136]
    __shared__ int cnt_l[64];
    unsigned short* A_l = (unsigned short*)&Aacc[0][0];   // row stride 136 shorts

    int tid = threadIdx.x;
    int blk = blockIdx.x;
    int lane = tid & 63, wave = tid >> 6;
    int g = lane >> 3, li = lane & 7;

    for (int i = tid; i < 64 * 68; i += 256) (&Aacc[0][0])[i] = 0.f;
    if (tid < 64) cnt_l[tid] = 0;
    __syncthreads();

    long hbase = (long)blk * EC;
    int start = hscan[hbase];
    int end = (blk + 1 < NB) ? hscan[hbase + EC]
                             : (hscan[(long)NB * EC - 1] + hist[(long)NB * EC - 1]);

    // edge-parallel gather: wave grabs 64 packed edges (coalesced), shfl
    // distributes one edge to each 8-lane group; lane li owns feats 8li..8li+7.
    for (int base = start + wave * 64; base < end; base += 256) {
        int nb = end - base; if (nb > 64) nb = 64;
        int pk = (lane < nb) ? bkt[base + lane] : 0;
#pragma unroll
        for (int t = 0; t < 8; ++t) {
            int idx = t * 8 + g;
            int p = __shfl(pk, idx);
            if (idx < nb) {
                int s = p & 0xFFFFF;
                int d6 = (p >> 20) & 63;
                uint4 u = *(const uint4*)(feat16 + (size_t)s * FEAT + 8 * li);
                f32x2 v0 = bfpair(u.x), v1 = bfpair(u.y);
                f32x2 v2 = bfpair(u.z), v3 = bfpair(u.w);
                float* ap = &Aacc[d6][8 * li];
                atomicAdd(ap + 0, v0.x); atomicAdd(ap + 1, v0.y);
                atomicAdd(ap + 2, v1.x); atomicAdd(ap + 3, v1.y);
                atomicAdd(ap + 4, v2.x); atomicAdd(ap + 5, v2.y);
                atomicAdd(ap + 6, v3.x); atomicAdd(ap + 7, v3.y);
                if (li == 0) atomicAdd(&cnt_l[d6], 1);
            }
        }
    }
    __syncthreads();

    // mean + in-place f32 -> bf16 (read-all -> sync -> write-all; same rows)
    {
        int r = tid >> 2, part = tid & 3;
        int c0 = part * 16;
        int dg = cnt_l[r];
        float inv = 1.0f / (float)(dg > 0 ? dg : 1);
        float tmp[16];
#pragma unroll
        for (int j = 0; j < 16; ++j) tmp[j] = Aacc[r][c0 + j] * inv;
        __syncthreads();
#pragma unroll
        for (int j = 0; j < 16; ++j) A_l[r * 136 + c0 + j] = f2bf(tmp[j]);
    }
    // stage root into cols 64..127 (bytes 128..255 of each 272 B row: disjoint
    // from the bf16 agg writes, and the f32 reads are fenced by the sync above)
#pragma unroll
    for (int i = 0; i < 2; ++i) {
        int ch = tid + i * 256;
        int r = ch >> 3, c = ch & 7;
        int row = blk * 64 + r;
        uint4 u = make_uint4(0, 0, 0, 0);
        if (row < N) u = ((const uint4*)(feat16 + (size_t)row * FEAT))[c];
        *(uint4*)&A_l[r * 136 + 64 + c * 8] = u;
    }
    __syncthreads();

    int r0 = wave * 16;
    int m = lane & 15, quad = lane >> 4;

    f32x4 acc0 = {0.f, 0.f, 0.f, 0.f};
    f32x4 acc1 = acc0, acc2 = acc0, acc3 = acc0;

    // B fragments straight from global (16 KB, L2-resident, shared by all blocks)
#pragma unroll
    for (int k0 = 0; k0 < 128; k0 += 32) {
        bf16x8 a  = *(const bf16x8*)&A_l[(r0 + m) * 136 + k0 + quad * 8];
        bf16x8 b0 = *(const bf16x8*)(Wt + ( 0 + m) * 128 + k0 + quad * 8);
        bf16x8 b1 = *(const bf16x8*)(Wt + (16 + m) * 128 + k0 + quad * 8);
        bf16x8 b2 = *(const bf16x8*)(Wt + (32 + m) * 128 + k0 + quad * 8);
        bf16x8 b3 = *(const bf16x8*)(Wt + (48 + m) * 128 + k0 + quad * 8);
        acc0 = __builtin_amdgcn_mfma_f32_16x16x32_bf16(a, b0, acc0, 0, 0, 0);
        acc1 = __builtin_amdgcn_mfma_f32_16x16x32_bf16(a, b1, acc1, 0, 0, 0);
        acc2 = __builtin_amdgcn_mfma_f32_16x16x32_bf16(a, b2, acc2, 0, 0, 0);
        acc3 = __builtin_amdgcn_mfma_f32_16x16x32_bf16(a, b3, acc3, 0, 0, 0);
    }
    __syncthreads();   // done reading A_l; reuse as C staging

    // epilogue: +bias, relu, bf16 -> A_l[row][col]  (C/D: col=lane&15, row=quad*4+reg)
#pragma unroll
    for (int c = 0; c < 4; ++c) {
        f32x4 av = (c == 0) ? acc0 : (c == 1) ? acc1 : (c == 2) ? acc2 : acc3;
        float bv = bias[c * 16 + m];
#pragma unroll
        for (int reg = 0; reg < 4; ++reg) {
            float v = fmaxf(av[reg] + bv, 0.f);
            A_l[(r0 + quad * 4 + reg) * 136 + c * 16 + m] = f2bf(v);
        }
    }
    __syncthreads();

    // coalesced store of C rows (layer 1 only): 512 uint4 chunks
    if (out16) {
#pragma unroll
        for (int i = 0; i < 2; ++i) {
            int ch = tid + i * 256;
            int r = ch >> 3, c = ch & 7;
            int row = blk * 64 + r;
            if (row < N)
                ((uint4*)(out16 + (size_t)row * FEAT))[c] = *(const uint4*)&A_l[r * 136 + c * 8];
        }
    }

    // fused final projection (layer 2): 4 threads per row, 16 feats each
    if (wl) {
        int r = tid >> 2, part = tid & 3;
        int row = blk * 64 + r;
        if (row < N) {
            float p0 = 0.f, p1 = 0.f;
#pragma unroll
            for (int j = 0; j < 16; ++j) {
                int f = part * 16 + j;
                float v = bflo2f(A_l[r * 136 + f]);
                p0 += v * wl[f * 2 + 0];
                p1 += v * wl[f * 2 + 1];
            }
            p0 += __shfl_down(p0, 2, 4); p0 += __shfl_down(p0, 1, 4);
            p1 += __shfl_down(p1, 2, 4); p1 += __shfl_down(p1, 1, 4);
            if (part == 0) {
                p0 += bl[0];
                p1 += bl[1];
                if (flags[0]) {
                    unsigned int o = ((unsigned int)f2bf(p1) << 16) | (unsigned int)f2bf(p0);
                    ((unsigned int*)out_final)[row] = o;
                } else {
                    ((float2*)out_final)[row] = make_float2(p0, p1);
                }
            }
        }
    }
}

extern "C" void kernel_launch(void* const* d_in, const int* in_sizes, int n_in,
                              void* d_out, int out_size, void* d_ws, size_t ws_size,
                              hipStream_t stream) {
    const void* x_in = d_in[0];
    const int*  ei32 = (const int*)d_in[1];

    int N = in_sizes[0] / FEAT;
    int E = in_sizes[1] / 2;
    int NB = (N + 63) >> 6;            // bucket = 64 nodes = one fused block
    int EC = (E + CHUNK - 1) / CHUNK;
    int HN = NB * EC;

    // workspace layout (p4 gone: no offs/cnt/srcs)
    unsigned short* x16   = (unsigned short*)d_ws;                 // N*64 bf16
    unsigned short* h16   = x16 + (size_t)N * FEAT;                // N*64
    unsigned short* Wt    = h16 + (size_t)N * FEAT;                // 16384
    float*          wbuf  = (float*)(Wt + 16384);                  // 16704
    int*            hist  = (int*)(wbuf + 16704);                  // HN
    int*            hscan = hist + HN;                             // HN
    int*            bsum  = hscan + HN;                            // <=1024
    int*            flags = bsum + 1024;                           // 16
    int*            bkt   = flags + 16;                            // E

    float* b1_32 = wbuf + 8192;
    float* b2_32 = wbuf + 16448;
    float* wl32  = wbuf + 16512;
    float* bl32  = wbuf + 16640;

    // 0. prep + P1 merged (role-split grid)
    int n8 = N * FEAT / 8;
    int pBlocks = (n8 + 255) / 256;
    if (pBlocks < 66) pBlocks = 66;
    prep_p1_kernel<<<pBlocks + EC, 256, 0, stream>>>(
        (const unsigned short*)x_in, ei32,
        d_in[2], d_in[3], d_in[4], d_in[5], d_in[6], d_in[7], d_in[8], d_in[9],
        wbuf, Wt, flags, x_in, x16, n8,
        hist, E, N, NB, EC, pBlocks);

    // 1. scan -> scatter
    int sB = (HN + 2047) / 2048;
    scan1_kernel<<<sB, 256, 0, stream>>>(hist, hscan, bsum, HN);
    scan3_kernel<<<sB, 256, 0, stream>>>(hscan, bsum, HN);
    p3_scatter_kernel<<<EC, 256, 0, stream>>>(ei32, hscan, bkt, E, N, NB, EC, flags);

    // 2. layer 1: fused aggregate + GEMM (x -> h16)
    sage_fused_kernel<<<NB, 256, 0, stream>>>(
        x_in, x16, bkt, hscan, hist, Wt, b1_32, h16, N, NB, EC,
        nullptr, nullptr, nullptr, flags, 1);

    // 3. layer 2: fused aggregate + GEMM + final projection
    sage_fused_kernel<<<NB, 256, 0, stream>>>(
        h16, h16, bkt, hscan, hist, Wt + 8192, b2_32, nullptr, N, NB, EC,
        wl32, bl32, d_out, flags, 0);
}

// Round 4
// 249.799 us; speedup vs baseline: 5.3711x; 5.3711x over previous
//
#include <hip/hip_runtime.h>
#include <hip/hip_bf16.h>

#define FEAT 64
#define CHUNK 8192   // edges per P1/P3 chunk
#define MAX_NB 1024  // max buckets (256 nodes/bucket -> N <= 262144)
#define SCAP 1792    // staged srcs per fused block (avg 1024 at deg 16)

typedef __attribute__((ext_vector_type(8))) short bf16x8;
typedef __attribute__((ext_vector_type(4))) float f32x4;
typedef __attribute__((ext_vector_type(2))) float f32x2;

// ---------- bf16 helpers ----------
__device__ __forceinline__ float bflo2f(unsigned int u) {
    union { unsigned int u; float f; } v; v.u = u << 16; return v.f;
}
__device__ __forceinline__ float bfhi2f(unsigned int u) {
    union { unsigned int u; float f; } v; v.u = u & 0xffff0000u; return v.f;
}
__device__ __forceinline__ unsigned short f2bf(float f) {
    union { float f; unsigned int u; } v; v.f = f;
    unsigned int u = v.u;
    u += 0x7fffu + ((u >> 16) & 1u);   // round-to-nearest-even
    return (unsigned short)(u >> 16);
}
__device__ __forceinline__ f32x2 bfpair(unsigned int u) {
    f32x2 r; r.x = bflo2f(u & 0xffffu); r.y = bfhi2f(u); return r;
}

// ---------- 0. prep + P1 merged: role-split grid ----------
// blocks [0, pB): dtype detect + weight conversion + x conversion
// blocks [pB, pB+EC): per-chunk bucket histogram (bucket = dst >> 8)
__global__ __launch_bounds__(256) void prep_p1_kernel(
    const unsigned short* __restrict__ xh, const int* __restrict__ ei32,
    const void* __restrict__ w1a, const void* __restrict__ w1r,
    const void* __restrict__ b1,  const void* __restrict__ w2a,
    const void* __restrict__ w2r, const void* __restrict__ b2,
    const void* __restrict__ wl,  const void* __restrict__ bl,
    float* __restrict__ wbuf, unsigned short* __restrict__ Wt,
    int* __restrict__ flags, const void* __restrict__ x_in,
    unsigned short* __restrict__ x16, int n8,
    int* __restrict__ hist, int E, int N, int NB, int EC, int pB) {
    __shared__ int lh[MAX_NB];
    __shared__ int cnt_bf, cnt_nz;
    int tid = threadIdx.x;

    if (blockIdx.x >= pB) {
        // ---- P1 role: histogram of chunk c (self-detect int64) ----
        int c = blockIdx.x - pB;
        if (tid == 0) cnt_nz = 0;
        for (int i = tid; i < NB; i += 256) lh[i] = 0;
        __syncthreads();
        if (ei32[tid * 2 + 1] != 0) atomicAdd(&cnt_nz, 1);
        __syncthreads();
        int idx64 = (cnt_nz < 8) ? 1 : 0;
        long base = (long)c * CHUNK;
#pragma unroll 4
        for (int j = 0; j < CHUNK / 256; ++j) {
            long e = base + j * 256 + tid;
            if (e < E) {
                int d = idx64 ? ei32[2 * ((long)E + e)] : ei32[(long)E + e];
                if ((unsigned)d < (unsigned)N)
                    atomicAdd(&lh[d >> 8], 1);
            }
        }
        __syncthreads();
        for (int k = tid; k < NB; k += 256) hist[(long)k * EC + c] = lh[k];
        return;
    }

    // ---- prep role ----
    if (tid == 0) { cnt_bf = 0; cnt_nz = 0; }
    __syncthreads();
    unsigned short h = xh[tid * 2];
    int e = (h >> 7) & 0xFF;
    if (e >= 110 && e <= 132) atomicAdd(&cnt_bf, 1);
    if (ei32[tid * 2 + 1] != 0) atomicAdd(&cnt_nz, 1);
    __syncthreads();
    int f0 = (cnt_bf >= 128) ? 1 : 0;
    if (blockIdx.x == 0 && tid == 0) {
        flags[0] = f0;
        flags[1] = (cnt_nz < 8) ? 1 : 0;
    }
    int i = blockIdx.x * 256 + tid;
    // weights (blocks 0..65): wbuf f32 + Wt bf16-transposed
    if (i < 16642) {
        const void* src; int off;
        if      (i < 4096)  { src = w1a; off = i; }
        else if (i < 8192)  { src = w1r; off = i - 4096; }
        else if (i < 8256)  { src = b1;  off = i - 8192; }
        else if (i < 12352) { src = w2a; off = i - 8256; }
        else if (i < 16448) { src = w2r; off = i - 12352; }
        else if (i < 16512) { src = b2;  off = i - 16448; }
        else if (i < 16640) { src = wl;  off = i - 16512; }
        else                { src = bl;  off = i - 16640; }
        float v = f0 ? bflo2f(((const unsigned short*)src)[off])
                     : ((const float*)src)[off];
        wbuf[i] = v;
        unsigned short hv = f2bf(v);   // exact round-trip when input was bf16
        if (i < 4096)                      Wt[(off & 63) * 128 + (off >> 6)] = hv;
        else if (i < 8192)                 Wt[(off & 63) * 128 + 64 + (off >> 6)] = hv;
        else if (i >= 8256 && i < 12352)   Wt[8192 + (off & 63) * 128 + (off >> 6)] = hv;
        else if (i >= 12352 && i < 16448)  Wt[8192 + (off & 63) * 128 + 64 + (off >> 6)] = hv;
    }
    // x -> bf16 (fp32 path only)
    if (!f0 && i < n8) {
        float4 a = ((const float4*)x_in)[2 * i];
        float4 b = ((const float4*)x_in)[2 * i + 1];
        uint4 o;
        o.x = (unsigned int)f2bf(a.x) | ((unsigned int)f2bf(a.y) << 16);
        o.y = (unsigned int)f2bf(a.z) | ((unsigned int)f2bf(a.w) << 16);
        o.z = (unsigned int)f2bf(b.x) | ((unsigned int)f2bf(b.y) << 16);
        o.w = (unsigned int)f2bf(b.z) | ((unsigned int)f2bf(b.w) << 16);
        ((uint4*)x16)[i] = o;
    }
}

// ---------- scan: multi-block scan1 + scan3 ----------
__global__ __launch_bounds__(256) void scan1_kernel(const int* __restrict__ in,
                                                    int* __restrict__ out,
                                                    int* __restrict__ blocksum, int n) {
    int tid = threadIdx.x;
    int base = blockIdx.x * 2048 + tid * 8;
    int v[8];
    int tsum = 0;
#pragma unroll
    for (int i = 0; i < 8; ++i) {
        v[i] = (base + i < n) ? in[base + i] : 0;
        tsum += v[i];
    }
    int lane = tid & 63;
    int x = tsum;
#pragma unroll
    for (int off = 1; off < 64; off <<= 1) {
        int y = __shfl_up(x, off);
        if (lane >= off) x += y;
    }
    __shared__ int wsum[4];
    int wave = tid >> 6;
    if (lane == 63) wsum[wave] = x;
    __syncthreads();
    int woff = 0;
#pragma unroll
    for (int w = 0; w < 4; ++w) if (w < wave) woff += wsum[w];
    int run = woff + x - tsum;
#pragma unroll
    for (int i = 0; i < 8; ++i) {
        if (base + i < n) out[base + i] = run;
        run += v[i];
    }
    if (tid == 255) blocksum[blockIdx.x] = woff + x;
}

// scan3: block bb owns [bb*2048, +2048) -> uniform prefix via one LDS reduce.
__global__ __launch_bounds__(256) void scan3_kernel(int* __restrict__ out,
                                                    const int* __restrict__ blocksum, int n) {
    int bb = blockIdx.x, tid = threadIdx.x;
    __shared__ int wsum[4];
    __shared__ int spre;
    int s = 0;
    for (int b = tid; b < bb; b += 256) s += blocksum[b];
#pragma unroll
    for (int off = 32; off > 0; off >>= 1) s += __shfl_down(s, off);
    int lane = tid & 63, wave = tid >> 6;
    if (lane == 0) wsum[wave] = s;
    __syncthreads();
    if (tid == 0) spre = wsum[0] + wsum[1] + wsum[2] + wsum[3];
    __syncthreads();
    int pre = spre;
    int base = bb * 2048;
#pragma unroll
    for (int k = 0; k < 8; ++k) {
        int i = base + k * 256 + tid;
        if (i < n) out[i] += pre;
    }
}

// ---------- P3: scatter packed edges into bucket-major order ----------
// packed = src | ((dst & 255) << 20)   (requires N < 2^20)
__global__ __launch_bounds__(256) void p3_scatter_kernel(
    const int* __restrict__ ei32, const int* __restrict__ hscan,
    int* __restrict__ bkt, int E, int N, int NB, int EC,
    const int* __restrict__ flags) {
    __shared__ int lh[MAX_NB];
    int tid = threadIdx.x, c = blockIdx.x;
    for (int i = tid; i < NB; i += 256) lh[i] = 0;
    __syncthreads();
    int idx64 = flags[1];
    long base = (long)c * CHUNK;
#pragma unroll 4
    for (int j = 0; j < CHUNK / 256; ++j) {
        long e = base + j * 256 + tid;
        if (e < E) {
            int s = idx64 ? ei32[2 * e]             : ei32[e];
            int d = idx64 ? ei32[2 * ((long)E + e)] : ei32[(long)E + e];
            if ((unsigned)d < (unsigned)N) {
                if ((unsigned)s >= (unsigned)N) s = 0;   // clamp (memory safety)
                int k = d >> 8;
                int r = atomicAdd(&lh[k], 1);
                bkt[hscan[(long)k * EC + c] + r] = s | ((d & 255) << 20);
            }
        }
    }
}

// ---------- P4: per-bucket CSR finalize ----------
__global__ __launch_bounds__(256) void p4_build_kernel(
    const int* __restrict__ bkt, const int* __restrict__ hscan, const int* __restrict__ hist,
    int* __restrict__ offs, int* __restrict__ cnt, int* __restrict__ srcs,
    int E, int N, int NB, int EC) {
    int k = blockIdx.x, tid = threadIdx.x;
    int start = hscan[(long)k * EC];
    int end = (k + 1 < NB) ? hscan[(long)(k + 1) * EC]
                           : (hscan[(long)NB * EC - 1] + hist[(long)NB * EC - 1]);
    __shared__ int lc[256], lheads[256], wsum[4];
    lc[tid] = 0;
    __syncthreads();
    for (int e = start + tid; e < end; e += 256)
        atomicAdd(&lc[(bkt[e] >> 20) & 255], 1);
    __syncthreads();
    int cv = lc[tid];
    int lane = tid & 63, wave = tid >> 6;
    int x = cv;
#pragma unroll
    for (int off = 1; off < 64; off <<= 1) {
        int y = __shfl_up(x, off);
        if (lane >= off) x += y;
    }
    if (lane == 63) wsum[wave] = x;
    __syncthreads();
    int woff = 0;
#pragma unroll
    for (int w = 0; w < 4; ++w) if (w < wave) woff += wsum[w];
    int excl = woff + x - cv;
    int gnode = k * 256 + tid;
    if (gnode < N) { offs[gnode] = start + excl; cnt[gnode] = cv; }
    lheads[tid] = excl;
    __syncthreads();
    for (int e = start + tid; e < end; e += 256) {
        int p = bkt[e];
        int d8 = (p >> 20) & 255;
        int pos = start + atomicAdd(&lheads[d8], 1);
        srcs[pos] = p & 0xFFFFF;
    }
}

// accumulate one uint4 (8 bf16 feats) into 4 f32x2 accumulators
#define ACC8(acc0, acc1, acc2, acc3, u) \
    acc0 += bfpair((u).x); acc1 += bfpair((u).y); \
    acc2 += bfpair((u).z); acc3 += bfpair((u).w);

// ---------- FUSED: dual-node interleaved gather + MFMA SAGE GEMM ----------
// Block = 64 nodes. 8-lane group owns TWO nodes (rows r and r+32), processed
// CONCURRENTLY in the main loop: two independent load chains -> ~8 gather
// loads in flight per wave (R1 had 4), degree-imbalance tails amortize.
// srcs staged in LDS (contiguous CSR range for the block's 64 nodes); B read
// from global (16 KB Wt, L2-resident) -> LDS 24.6 KB -> 6 blocks/CU.
// NO min-waves launch bound (round-2 lesson: reg cap serialized the gather).
__global__ __launch_bounds__(256) void sage_fused_kernel(
    const void* __restrict__ feat_raw, const unsigned short* __restrict__ feat_ws,
    const int* __restrict__ srcs, const int* __restrict__ offs,
    const int* __restrict__ cnt,
    const unsigned short* __restrict__ Wt, const float* __restrict__ bias,
    unsigned short* __restrict__ out16, int N,
    const float* __restrict__ wl, const float* __restrict__ bl,
    void* __restrict__ out_final, const int* __restrict__ flags, int sel) {

    const unsigned short* feat16 =
        (sel && !flags[0]) ? feat_ws : (const unsigned short*)feat_raw;

    __shared__ unsigned short A_l[64][136];   // stride 68 dwords -> 2-way (free)
    __shared__ int srcs_l[SCAP];              // staged edge list for 64 nodes

    int tid = threadIdx.x;
    int blk = blockIdx.x;

    // stage srcs: contiguous range [offs[first], offs[last]+cnt[last])
    int first = blk * 64;
    int lastN = first + 63; if (lastN >= N) lastN = N - 1;
    int eb = offs[first];
    int eEnd = offs[lastN] + cnt[lastN];
    int nE = eEnd - eb; if (nE > SCAP) nE = SCAP;
    for (int i = tid; i < nE; i += 256) srcs_l[i] = srcs[eb + i];

    // stage root half of A (cols 64..127): 512 uint4 chunks
#pragma unroll
    for (int i = 0; i < 2; ++i) {
        int ch = tid + i * 256;
        int r = ch >> 3, c = ch & 7;
        int row = blk * 64 + r;
        uint4 u = make_uint4(0, 0, 0, 0);
        if (row < N) u = ((const uint4*)(feat16 + (size_t)row * FEAT))[c];
        *(uint4*)&A_l[r][64 + c * 8] = u;
    }
    __syncthreads();   // srcs_l ready

    int lane = tid & 63;
    int wave = tid >> 6;
    int g = lane >> 3;
    int li = lane & 7;

    // dual-node gather: group handles rows rA = wave*8+g and rB = rA+32
    {
        int rA = wave * 8 + g, rB = rA + 32;
        int nodeA = blk * 64 + rA, nodeB = blk * 64 + rB;
        int degA = 0, degB = 0;
        const int* pA = srcs;
        const int* pB = srcs;
        if (nodeA < N) {
            int st = offs[nodeA]; degA = cnt[nodeA];
            int ba = st - eb;
            pA = (ba + degA <= nE) ? (const int*)(srcs_l + ba) : (srcs + st);
        }
        if (nodeB < N) {
            int st = offs[nodeB]; degB = cnt[nodeB];
            int bb = st - eb;
            pB = (bb + degB <= nE) ? (const int*)(srcs_l + bb) : (srcs + st);
        }
        f32x2 a0 = {0.f, 0.f}, a1 = a0, a2 = a0, a3 = a0;
        f32x2 b0 = a0, b1 = a0, b2 = a0, b3 = a0;

        int dmin = degA < degB ? degA : degB;
        int j = 0;
        // interleaved main loop: 2x2 loads per iteration, two independent chains
        for (; j + 2 <= dmin; j += 2) {
            int sA0 = pA[j], sA1 = pA[j + 1];
            int sB0 = pB[j], sB1 = pB[j + 1];
            uint4 uA0 = *(const uint4*)(feat16 + (size_t)sA0 * FEAT + 8 * li);
            uint4 uA1 = *(const uint4*)(feat16 + (size_t)sA1 * FEAT + 8 * li);
            uint4 uB0 = *(const uint4*)(feat16 + (size_t)sB0 * FEAT + 8 * li);
            uint4 uB1 = *(const uint4*)(feat16 + (size_t)sB1 * FEAT + 8 * li);
            ACC8(a0, a1, a2, a3, uA0); ACC8(a0, a1, a2, a3, uA1);
            ACC8(b0, b1, b2, b3, uB0); ACC8(b0, b1, b2, b3, uB1);
        }
        int jA = j, jB = j;
        // A tail (unroll-4 then scalar)
        for (; jA + 4 <= degA; jA += 4) {
            int s0 = pA[jA], s1 = pA[jA + 1], s2 = pA[jA + 2], s3 = pA[jA + 3];
            uint4 u0 = *(const uint4*)(feat16 + (size_t)s0 * FEAT + 8 * li);
            uint4 u1 = *(const uint4*)(feat16 + (size_t)s1 * FEAT + 8 * li);
            uint4 u2 = *(const uint4*)(feat16 + (size_t)s2 * FEAT + 8 * li);
            uint4 u3 = *(const uint4*)(feat16 + (size_t)s3 * FEAT + 8 * li);
            ACC8(a0, a1, a2, a3, u0); ACC8(a0, a1, a2, a3, u1);
            ACC8(a0, a1, a2, a3, u2); ACC8(a0, a1, a2, a3, u3);
        }
        for (; jA < degA; ++jA) {
            int s = pA[jA];
            uint4 u = *(const uint4*)(feat16 + (size_t)s * FEAT + 8 * li);
            ACC8(a0, a1, a2, a3, u);
        }
        // B tail
        for (; jB + 4 <= degB; jB += 4) {
            int s0 = pB[jB], s1 = pB[jB + 1], s2 = pB[jB + 2], s3 = pB[jB + 3];
            uint4 u0 = *(const uint4*)(feat16 + (size_t)s0 * FEAT + 8 * li);
            uint4 u1 = *(const uint4*)(feat16 + (size_t)s1 * FEAT + 8 * li);
            uint4 u2 = *(const uint4*)(feat16 + (size_t)s2 * FEAT + 8 * li);
            uint4 u3 = *(const uint4*)(feat16 + (size_t)s3 * FEAT + 8 * li);
            ACC8(b0, b1, b2, b3, u0); ACC8(b0, b1, b2, b3, u1);
            ACC8(b0, b1, b2, b3, u2); ACC8(b0, b1, b2, b3, u3);
        }
        for (; jB < degB; ++jB) {
            int s = pB[jB];
            uint4 u = *(const uint4*)(feat16 + (size_t)s * FEAT + 8 * li);
            ACC8(b0, b1, b2, b3, u);
        }

        float invA = 1.0f / (float)(degA > 0 ? degA : 1);
        float invB = 1.0f / (float)(degB > 0 ? degB : 1);
        uint4 oA, oB;
        oA.x = (unsigned)f2bf(a0.x * invA) | ((unsigned)f2bf(a0.y * invA) << 16);
        oA.y = (unsigned)f2bf(a1.x * invA) | ((unsigned)f2bf(a1.y * invA) << 16);
        oA.z = (unsigned)f2bf(a2.x * invA) | ((unsigned)f2bf(a2.y * invA) << 16);
        oA.w = (unsigned)f2bf(a3.x * invA) | ((unsigned)f2bf(a3.y * invA) << 16);
        oB.x = (unsigned)f2bf(b0.x * invB) | ((unsigned)f2bf(b0.y * invB) << 16);
        oB.y = (unsigned)f2bf(b1.x * invB) | ((unsigned)f2bf(b1.y * invB) << 16);
        oB.z = (unsigned)f2bf(b2.x * invB) | ((unsigned)f2bf(b2.y * invB) << 16);
        oB.w = (unsigned)f2bf(b3.x * invB) | ((unsigned)f2bf(b3.y * invB) << 16);
        *(uint4*)&A_l[rA][8 * li] = oA;
        *(uint4*)&A_l[rB][8 * li] = oB;
    }
    __syncthreads();

    int r0 = wave * 16;
    int m = lane & 15, quad = lane >> 4;

    f32x4 acc0 = {0.f, 0.f, 0.f, 0.f};
    f32x4 acc1 = acc0, acc2 = acc0, acc3 = acc0;

    // B fragments straight from global (L2-hit: 16 KB shared by all blocks)
#pragma unroll
    for (int k0 = 0; k0 < 128; k0 += 32) {
        bf16x8 a  = *(const bf16x8*)&A_l[r0 + m][k0 + quad * 8];
        bf16x8 w0 = *(const bf16x8*)(Wt + ( 0 + m) * 128 + k0 + quad * 8);
        bf16x8 w1 = *(const bf16x8*)(Wt + (16 + m) * 128 + k0 + quad * 8);
        bf16x8 w2 = *(const bf16x8*)(Wt + (32 + m) * 128 + k0 + quad * 8);
        bf16x8 w3 = *(const bf16x8*)(Wt + (48 + m) * 128 + k0 + quad * 8);
        acc0 = __builtin_amdgcn_mfma_f32_16x16x32_bf16(a, w0, acc0, 0, 0, 0);
        acc1 = __builtin_amdgcn_mfma_f32_16x16x32_bf16(a, w1, acc1, 0, 0, 0);
        acc2 = __builtin_amdgcn_mfma_f32_16x16x32_bf16(a, w2, acc2, 0, 0, 0);
        acc3 = __builtin_amdgcn_mfma_f32_16x16x32_bf16(a, w3, acc3, 0, 0, 0);
    }
    __syncthreads();   // done reading A_l; reuse as C staging

    // epilogue: +bias, relu, bf16 -> A_l[row][col]  (C/D: col=lane&15, row=quad*4+reg)
#pragma unroll
    for (int c = 0; c < 4; ++c) {
        f32x4 av = (c == 0) ? acc0 : (c == 1) ? acc1 : (c == 2) ? acc2 : acc3;
        float bv = bias[c * 16 + m];
#pragma unroll
        for (int reg = 0; reg < 4; ++reg) {
            float v = fmaxf(av[reg] + bv, 0.f);
            A_l[r0 + quad * 4 + reg][c * 16 + m] = f2bf(v);
        }
    }
    __syncthreads();

    // coalesced store of C rows (layer 1 only): 512 uint4 chunks
    if (out16) {
#pragma unroll
        for (int i = 0; i < 2; ++i) {
            int ch = tid + i * 256;
            int r = ch >> 3, c = ch & 7;
            int row = blk * 64 + r;
            if (row < N)
                ((uint4*)(out16 + (size_t)row * FEAT))[c] = *(const uint4*)&A_l[r][c * 8];
        }
    }

    // fused final projection (layer 2): 4 threads per row, 16 feats each
    if (wl) {
        int r = tid >> 2, part = tid & 3;
        int row = blk * 64 + r;
        if (row < N) {
            float p0 = 0.f, p1 = 0.f;
#pragma unroll
            for (int j = 0; j < 16; ++j) {
                int f = part * 16 + j;
                float v = bflo2f(A_l[r][f]);
                p0 += v * wl[f * 2 + 0];
                p1 += v * wl[f * 2 + 1];
            }
            p0 += __shfl_down(p0, 2, 4); p0 += __shfl_down(p0, 1, 4);
            p1 += __shfl_down(p1, 2, 4); p1 += __shfl_down(p1, 1, 4);
            if (part == 0) {
                p0 += bl[0];
                p1 += bl[1];
                if (flags[0]) {
                    unsigned int o = ((unsigned int)f2bf(p1) << 16) | (unsigned int)f2bf(p0);
                    ((unsigned int*)out_final)[row] = o;
                } else {
                    ((float2*)out_final)[row] = make_float2(p0, p1);
                }
            }
        }
    }
}

extern "C" void kernel_launch(void* const* d_in, const int* in_sizes, int n_in,
                              void* d_out, int out_size, void* d_ws, size_t ws_size,
                              hipStream_t stream) {
    const void* x_in = d_in[0];
    const int*  ei32 = (const int*)d_in[1];

    int N = in_sizes[0] / FEAT;
    int E = in_sizes[1] / 2;
    int NB = (N + 255) >> 8;
    int EC = (E + CHUNK - 1) / CHUNK;
    int HN = NB * EC;

    // workspace layout
    unsigned short* x16   = (unsigned short*)d_ws;                 // N*64 bf16
    unsigned short* h16   = x16 + (size_t)N * FEAT;                // N*64
    unsigned short* Wt    = h16 + (size_t)N * FEAT;                // 16384
    float*          wbuf  = (float*)(Wt + 16384);                  // 16704
    int*            hist  = (int*)(wbuf + 16704);                  // HN
    int*            hscan = hist + HN;                             // HN
    int*            bsum  = hscan + HN;                            // <=1024
    int*            flags = bsum + 1024;                           // 16
    int*            offs  = flags + 16;                            // N
    int*            cnt   = offs + N;                              // N
    int*            bkt   = cnt + N;                               // E
    int*            srcs  = bkt + E;                               // E

    float* b1_32 = wbuf + 8192;
    float* b2_32 = wbuf + 16448;
    float* wl32  = wbuf + 16512;
    float* bl32  = wbuf + 16640;

    // 0. prep + P1 merged (role-split grid)
    int n8 = N * FEAT / 8;
    int pBlocks = (n8 + 255) / 256;
    if (pBlocks < 66) pBlocks = 66;
    prep_p1_kernel<<<pBlocks + EC, 256, 0, stream>>>(
        (const unsigned short*)x_in, ei32,
        d_in[2], d_in[3], d_in[4], d_in[5], d_in[6], d_in[7], d_in[8], d_in[9],
        wbuf, Wt, flags, x_in, x16, n8,
        hist, E, N, NB, EC, pBlocks);

    // 1. scan -> scatter -> finalize
    int sB = (HN + 2047) / 2048;
    scan1_kernel<<<sB, 256, 0, stream>>>(hist, hscan, bsum, HN);
    scan3_kernel<<<sB, 256, 0, stream>>>(hscan, bsum, HN);
    p3_scatter_kernel<<<EC, 256, 0, stream>>>(ei32, hscan, bkt, E, N, NB, EC, flags);
    p4_build_kernel<<<NB, 256, 0, stream>>>(bkt, hscan, hist, offs, cnt, srcs, E, N, NB, EC);

    int gBlocks = (N + 63) / 64;

    // 2. layer 1: fused aggregate + GEMM (x -> h16)
    sage_fused_kernel<<<gBlocks, 256, 0, stream>>>(
        x_in, x16, srcs, offs, cnt, Wt, b1_32, h16, N,
        nullptr, nullptr, nullptr, flags, 1);

    // 3. layer 2: fused aggregate + GEMM + final projection
    sage_fused_kernel<<<gBlocks, 256, 0, stream>>>(
        h16, h16, srcs, offs, cnt, Wt + 8192, b2_32, nullptr, N,
        wl32, bl32, d_out, flags, 0);
}

// Round 5
// 231.966 us; speedup vs baseline: 5.7841x; 1.0769x over previous
//
#include <hip/hip_runtime.h>
#include <hip/hip_bf16.h>

#define FEAT 64
#define CHUNK 2048   // edges per P1/P3 chunk (782 blocks ~ 3/CU)
#define MAX_NB 1024  // max buckets (256 nodes/bucket -> N <= 262144)

typedef __attribute__((ext_vector_type(8))) short bf16x8;
typedef __attribute__((ext_vector_type(4))) float f32x4;
typedef __attribute__((ext_vector_type(2))) float f32x2;

// ---------- bf16 helpers ----------
__device__ __forceinline__ float bflo2f(unsigned int u) {
    union { unsigned int u; float f; } v; v.u = u << 16; return v.f;
}
__device__ __forceinline__ float bfhi2f(unsigned int u) {
    union { unsigned int u; float f; } v; v.u = u & 0xffff0000u; return v.f;
}
__device__ __forceinline__ unsigned short f2bf(float f) {
    union { float f; unsigned int u; } v; v.f = f;
    unsigned int u = v.u;
    u += 0x7fffu + ((u >> 16) & 1u);   // round-to-nearest-even
    return (unsigned short)(u >> 16);
}
__device__ __forceinline__ f32x2 bfpair(unsigned int u) {
    f32x2 r; r.x = bflo2f(u & 0xffffu); r.y = bfhi2f(u); return r;
}

// ---------- 0. prep + P1 merged: role-split grid ----------
// blocks [0, pB): dtype detect + weight conversion + x conversion
// blocks [pB, pB+EC): per-chunk bucket histogram (bucket = dst >> 8)
__global__ __launch_bounds__(256) void prep_p1_kernel(
    const unsigned short* __restrict__ xh, const int* __restrict__ ei32,
    const void* __restrict__ w1a, const void* __restrict__ w1r,
    const void* __restrict__ b1,  const void* __restrict__ w2a,
    const void* __restrict__ w2r, const void* __restrict__ b2,
    const void* __restrict__ wl,  const void* __restrict__ bl,
    float* __restrict__ wbuf, unsigned short* __restrict__ Wt,
    int* __restrict__ flags, const void* __restrict__ x_in,
    unsigned short* __restrict__ x16, int n8,
    int* __restrict__ hist, int E, int N, int NB, int EC, int pB) {
    __shared__ int lh[MAX_NB];
    __shared__ int cnt_bf, cnt_nz;
    int tid = threadIdx.x;

    if (blockIdx.x >= pB) {
        // ---- P1 role: histogram of chunk c (self-detect int64) ----
        int c = blockIdx.x - pB;
        if (tid == 0) cnt_nz = 0;
        for (int i = tid; i < NB; i += 256) lh[i] = 0;
        __syncthreads();
        if (ei32[tid * 2 + 1] != 0) atomicAdd(&cnt_nz, 1);
        __syncthreads();
        int idx64 = (cnt_nz < 8) ? 1 : 0;
        long base = (long)c * CHUNK;
#pragma unroll 4
        for (int j = 0; j < CHUNK / 256; ++j) {
            long e = base + j * 256 + tid;
            if (e < E) {
                int d = idx64 ? ei32[2 * ((long)E + e)] : ei32[(long)E + e];
                if ((unsigned)d < (unsigned)N)
                    atomicAdd(&lh[d >> 8], 1);
            }
        }
        __syncthreads();
        for (int k = tid; k < NB; k += 256) hist[(long)k * EC + c] = lh[k];
        return;
    }

    // ---- prep role ----
    if (tid == 0) { cnt_bf = 0; cnt_nz = 0; }
    __syncthreads();
    unsigned short h = xh[tid * 2];
    int e = (h >> 7) & 0xFF;
    if (e >= 110 && e <= 132) atomicAdd(&cnt_bf, 1);
    if (ei32[tid * 2 + 1] != 0) atomicAdd(&cnt_nz, 1);
    __syncthreads();
    int f0 = (cnt_bf >= 128) ? 1 : 0;
    if (blockIdx.x == 0 && tid == 0) {
        flags[0] = f0;
        flags[1] = (cnt_nz < 8) ? 1 : 0;
    }
    int i = blockIdx.x * 256 + tid;
    // weights (blocks 0..65): wbuf f32 + Wt bf16-transposed
    if (i < 16642) {
        const void* src; int off;
        if      (i < 4096)  { src = w1a; off = i; }
        else if (i < 8192)  { src = w1r; off = i - 4096; }
        else if (i < 8256)  { src = b1;  off = i - 8192; }
        else if (i < 12352) { src = w2a; off = i - 8256; }
        else if (i < 16448) { src = w2r; off = i - 12352; }
        else if (i < 16512) { src = b2;  off = i - 16448; }
        else if (i < 16640) { src = wl;  off = i - 16512; }
        else                { src = bl;  off = i - 16640; }
        float v = f0 ? bflo2f(((const unsigned short*)src)[off])
                     : ((const float*)src)[off];
        wbuf[i] = v;
        unsigned short hv = f2bf(v);   // exact round-trip when input was bf16
        if (i < 4096)                      Wt[(off & 63) * 128 + (off >> 6)] = hv;
        else if (i < 8192)                 Wt[(off & 63) * 128 + 64 + (off >> 6)] = hv;
        else if (i >= 8256 && i < 12352)   Wt[8192 + (off & 63) * 128 + (off >> 6)] = hv;
        else if (i >= 12352 && i < 16448)  Wt[8192 + (off & 63) * 128 + 64 + (off >> 6)] = hv;
    }
    // x -> bf16 (fp32 path only)
    if (!f0 && i < n8) {
        float4 a = ((const float4*)x_in)[2 * i];
        float4 b = ((const float4*)x_in)[2 * i + 1];
        uint4 o;
        o.x = (unsigned int)f2bf(a.x) | ((unsigned int)f2bf(a.y) << 16);
        o.y = (unsigned int)f2bf(a.z) | ((unsigned int)f2bf(a.w) << 16);
        o.z = (unsigned int)f2bf(b.x) | ((unsigned int)f2bf(b.y) << 16);
        o.w = (unsigned int)f2bf(b.z) | ((unsigned int)f2bf(b.w) << 16);
        ((uint4*)x16)[i] = o;
    }
}

// ---------- scan: multi-block scan1 + scan3 ----------
__global__ __launch_bounds__(256) void scan1_kernel(const int* __restrict__ in,
                                                    int* __restrict__ out,
                                                    int* __restrict__ blocksum, int n) {
    int tid = threadIdx.x;
    int base = blockIdx.x * 2048 + tid * 8;
    int v[8];
    int tsum = 0;
#pragma unroll
    for (int i = 0; i < 8; ++i) {
        v[i] = (base + i < n) ? in[base + i] : 0;
        tsum += v[i];
    }
    int lane = tid & 63;
    int x = tsum;
#pragma unroll
    for (int off = 1; off < 64; off <<= 1) {
        int y = __shfl_up(x, off);
        if (lane >= off) x += y;
    }
    __shared__ int wsum[4];
    int wave = tid >> 6;
    if (lane == 63) wsum[wave] = x;
    __syncthreads();
    int woff = 0;
#pragma unroll
    for (int w = 0; w < 4; ++w) if (w < wave) woff += wsum[w];
    int run = woff + x - tsum;
#pragma unroll
    for (int i = 0; i < 8; ++i) {
        if (base + i < n) out[base + i] = run;
        run += v[i];
    }
    if (tid == 255) blocksum[blockIdx.x] = woff + x;
}

// scan3: block bb owns [bb*2048, +2048) -> uniform prefix via one LDS reduce.
__global__ __launch_bounds__(256) void scan3_kernel(int* __restrict__ out,
                                                    const int* __restrict__ blocksum, int n) {
    int bb = blockIdx.x, tid = threadIdx.x;
    __shared__ int wsum[4];
    __shared__ int spre;
    int s = 0;
    for (int b = tid; b < bb; b += 256) s += blocksum[b];
#pragma unroll
    for (int off = 32; off > 0; off >>= 1) s += __shfl_down(s, off);
    int lane = tid & 63, wave = tid >> 6;
    if (lane == 0) wsum[wave] = s;
    __syncthreads();
    if (tid == 0) spre = wsum[0] + wsum[1] + wsum[2] + wsum[3];
    __syncthreads();
    int pre = spre;
    int base = bb * 2048;
#pragma unroll
    for (int k = 0; k < 8; ++k) {
        int i = base + k * 256 + tid;
        if (i < n) out[i] += pre;
    }
}

// ---------- P3: scatter packed edges into bucket-major order ----------
// packed = src | ((dst & 255) << 20)   (requires N < 2^20)
__global__ __launch_bounds__(256) void p3_scatter_kernel(
    const int* __restrict__ ei32, const int* __restrict__ hscan,
    int* __restrict__ bkt, int E, int N, int NB, int EC,
    const int* __restrict__ flags) {
    __shared__ int lh[MAX_NB];
    int tid = threadIdx.x, c = blockIdx.x;
    for (int i = tid; i < NB; i += 256) lh[i] = 0;
    __syncthreads();
    int idx64 = flags[1];
    long base = (long)c * CHUNK;
#pragma unroll 4
    for (int j = 0; j < CHUNK / 256; ++j) {
        long e = base + j * 256 + tid;
        if (e < E) {
            int s = idx64 ? ei32[2 * e]             : ei32[e];
            int d = idx64 ? ei32[2 * ((long)E + e)] : ei32[(long)E + e];
            if ((unsigned)d < (unsigned)N) {
                if ((unsigned)s >= (unsigned)N) s = 0;   // clamp (memory safety)
                int k = d >> 8;
                int r = atomicAdd(&lh[k], 1);
                bkt[hscan[(long)k * EC + c] + r] = s | ((d & 255) << 20);
            }
        }
    }
}

// ---------- P4: per-bucket CSR finalize ----------
__global__ __launch_bounds__(256) void p4_build_kernel(
    const int* __restrict__ bkt, const int* __restrict__ hscan, const int* __restrict__ hist,
    int* __restrict__ offs, int* __restrict__ cnt, int* __restrict__ srcs,
    int E, int N, int NB, int EC) {
    int k = blockIdx.x, tid = threadIdx.x;
    int start = hscan[(long)k * EC];
    int end = (k + 1 < NB) ? hscan[(long)(k + 1) * EC]
                           : (hscan[(long)NB * EC - 1] + hist[(long)NB * EC - 1]);
    __shared__ int lc[256], lheads[256], wsum[4];
    lc[tid] = 0;
    __syncthreads();
    for (int e = start + tid; e < end; e += 256)
        atomicAdd(&lc[(bkt[e] >> 20) & 255], 1);
    __syncthreads();
    int cv = lc[tid];
    int lane = tid & 63, wave = tid >> 6;
    int x = cv;
#pragma unroll
    for (int off = 1; off < 64; off <<= 1) {
        int y = __shfl_up(x, off);
        if (lane >= off) x += y;
    }
    if (lane == 63) wsum[wave] = x;
    __syncthreads();
    int woff = 0;
#pragma unroll
    for (int w = 0; w < 4; ++w) if (w < wave) woff += wsum[w];
    int excl = woff + x - cv;
    int gnode = k * 256 + tid;
    if (gnode < N) { offs[gnode] = start + excl; cnt[gnode] = cv; }
    lheads[tid] = excl;
    __syncthreads();
    for (int e = start + tid; e < end; e += 256) {
        int p = bkt[e];
        int d8 = (p >> 20) & 255;
        int pos = start + atomicAdd(&lheads[d8], 1);
        srcs[pos] = p & 0xFFFFF;
    }
}

// ---------- 5+6 FUSED: aggregate + MFMA SAGE GEMM (one block = 64 nodes) ----------
// R5 = R1's proven gather (single node per 8-lane group, srcs global broadcast,
// unroll-4 — best measured at 46 us) with the ROOT-STAGING PHASE DELETED:
// the MFMA A-fragment for k0>=64 is a direct aligned 16 B global load from the
// block's own rows (L2-resident), so root never needs LDS. A_l shrinks
// [64][136] -> [64][72]; LDS 34816 -> 26624 B -> 6 blocks/CU (was 4), one
// fewer barrier-synced phase. Gather registers untouched (round-2 lesson:
// never cap regs; round-4 lesson: don't add a second accumulator chain).
__global__ __launch_bounds__(256) void sage_fused_kernel(
    const void* __restrict__ feat_raw, const unsigned short* __restrict__ feat_ws,
    const int* __restrict__ srcs, const int* __restrict__ offs,
    const int* __restrict__ cnt,
    const unsigned short* __restrict__ Wt, const float* __restrict__ bias,
    unsigned short* __restrict__ out16, int N,
    const float* __restrict__ wl, const float* __restrict__ bl,
    void* __restrict__ out_final, const int* __restrict__ flags, int sel) {

    // sel=1 (layer 1): bf16 input -> read x_in directly, else converted x16.
    // sel=0 (layer 2): feat_raw == feat_ws == h16.
    const unsigned short* feat16 =
        (sel && !flags[0]) ? feat_ws : (const unsigned short*)feat_raw;

    __shared__ unsigned short A_l[64][72];    // agg half only; reused as C staging
    __shared__ unsigned short B_l[64][136];   // Wt[n][k]

    int tid = threadIdx.x;
    int blk = blockIdx.x;

    // stage B: 1024 chunks of 8 shorts (B is 64 rows x 128 k)
#pragma unroll
    for (int i = 0; i < 4; ++i) {
        int ch = tid + i * 256;
        int n = ch >> 4, kc = ch & 15;
        *(uint4*)&B_l[n][kc * 8] = *(const uint4*)(Wt + n * 128 + kc * 8);
    }

    int lane = tid & 63;
    int wave = tid >> 6;
    int g = lane >> 3;
    int li = lane & 7;

    // gather-aggregate into A_l cols 0..63 (2 passes of 32 nodes) — R1-exact
    for (int pass = 0; pass < 2; ++pass) {
        int r = pass * 32 + wave * 8 + g;
        int node = blk * 64 + r;
        f32x2 a0 = {0.f, 0.f}, a1 = a0, a2 = a0, a3 = a0;
        int deg = 0;
        if (node < N) {
            int start = offs[node];
            deg = cnt[node];
            int j = 0;
            for (; j + 4 <= deg; j += 4) {
                int s0 = srcs[start + j];
                int s1 = srcs[start + j + 1];
                int s2 = srcs[start + j + 2];
                int s3 = srcs[start + j + 3];
                uint4 u0 = *(const uint4*)(feat16 + (size_t)s0 * FEAT + 8 * li);
                uint4 u1 = *(const uint4*)(feat16 + (size_t)s1 * FEAT + 8 * li);
                uint4 u2 = *(const uint4*)(feat16 + (size_t)s2 * FEAT + 8 * li);
                uint4 u3 = *(const uint4*)(feat16 + (size_t)s3 * FEAT + 8 * li);
                a0 += bfpair(u0.x); a1 += bfpair(u0.y); a2 += bfpair(u0.z); a3 += bfpair(u0.w);
                a0 += bfpair(u1.x); a1 += bfpair(u1.y); a2 += bfpair(u1.z); a3 += bfpair(u1.w);
                a0 += bfpair(u2.x); a1 += bfpair(u2.y); a2 += bfpair(u2.z); a3 += bfpair(u2.w);
                a0 += bfpair(u3.x); a1 += bfpair(u3.y); a2 += bfpair(u3.z); a3 += bfpair(u3.w);
            }
            for (; j < deg; ++j) {
                int s = srcs[start + j];
                uint4 u = *(const uint4*)(feat16 + (size_t)s * FEAT + 8 * li);
                a0 += bfpair(u.x); a1 += bfpair(u.y); a2 += bfpair(u.z); a3 += bfpair(u.w);
            }
        }
        float inv = 1.0f / (float)(deg > 0 ? deg : 1);
        uint4 o;
        o.x = (unsigned)f2bf(a0.x * inv) | ((unsigned)f2bf(a0.y * inv) << 16);
        o.y = (unsigned)f2bf(a1.x * inv) | ((unsigned)f2bf(a1.y * inv) << 16);
        o.z = (unsigned)f2bf(a2.x * inv) | ((unsigned)f2bf(a2.y * inv) << 16);
        o.w = (unsigned)f2bf(a3.x * inv) | ((unsigned)f2bf(a3.y * inv) << 16);
        *(uint4*)&A_l[r][8 * li] = o;
    }
    __syncthreads();

    int r0 = wave * 16;
    int m = lane & 15, quad = lane >> 4;

    // root row for the k0>=64 fragments: direct global load, clamped (rows >= N
    // produce don't-care C rows that are never stored, but must not fault)
    int arow = blk * 64 + r0 + m;
    if (arow >= N) arow = 0;
    const unsigned short* rootp = feat16 + (size_t)arow * FEAT + quad * 8;

    f32x4 acc0 = {0.f, 0.f, 0.f, 0.f};
    f32x4 acc1 = acc0, acc2 = acc0, acc3 = acc0;

#pragma unroll
    for (int k0 = 0; k0 < 128; k0 += 32) {
        bf16x8 a;
        if (k0 < 64) a = *(const bf16x8*)&A_l[r0 + m][k0 + quad * 8];
        else         a = *(const bf16x8*)(rootp + (k0 - 64));
        bf16x8 b0 = *(const bf16x8*)&B_l[ 0 + m][k0 + quad * 8];
        bf16x8 b1 = *(const bf16x8*)&B_l[16 + m][k0 + quad * 8];
        bf16x8 b2 = *(const bf16x8*)&B_l[32 + m][k0 + quad * 8];
        bf16x8 b3 = *(const bf16x8*)&B_l[48 + m][k0 + quad * 8];
        acc0 = __builtin_amdgcn_mfma_f32_16x16x32_bf16(a, b0, acc0, 0, 0, 0);
        acc1 = __builtin_amdgcn_mfma_f32_16x16x32_bf16(a, b1, acc1, 0, 0, 0);
        acc2 = __builtin_amdgcn_mfma_f32_16x16x32_bf16(a, b2, acc2, 0, 0, 0);
        acc3 = __builtin_amdgcn_mfma_f32_16x16x32_bf16(a, b3, acc3, 0, 0, 0);
    }
    __syncthreads();   // done reading A_l; reuse as C staging

    // epilogue: +bias, relu, bf16 -> A_l[row][col]  (C/D: col=lane&15, row=quad*4+reg)
#pragma unroll
    for (int c = 0; c < 4; ++c) {
        f32x4 av = (c == 0) ? acc0 : (c == 1) ? acc1 : (c == 2) ? acc2 : acc3;
        float bv = bias[c * 16 + m];
#pragma unroll
        for (int reg = 0; reg < 4; ++reg) {
            float v = fmaxf(av[reg] + bv, 0.f);
            A_l[r0 + quad * 4 + reg][c * 16 + m] = f2bf(v);
        }
    }
    __syncthreads();

    // coalesced store of C rows (layer 1 only): 512 uint4 chunks
    if (out16) {
#pragma unroll
        for (int i = 0; i < 2; ++i) {
            int ch = tid + i * 256;
            int r = ch >> 3, c = ch & 7;
            int row = blk * 64 + r;
            if (row < N)
                ((uint4*)(out16 + (size_t)row * FEAT))[c] = *(const uint4*)&A_l[r][c * 8];
        }
    }

    // fused final projection (layer 2): 4 threads per row, 16 feats each
    if (wl) {
        int r = tid >> 2, part = tid & 3;
        int row = blk * 64 + r;
        if (row < N) {
            float p0 = 0.f, p1 = 0.f;
#pragma unroll
            for (int j = 0; j < 16; ++j) {
                int f = part * 16 + j;
                float v = bflo2f(A_l[r][f]);
                p0 += v * wl[f * 2 + 0];
                p1 += v * wl[f * 2 + 1];
            }
            p0 += __shfl_down(p0, 2, 4); p0 += __shfl_down(p0, 1, 4);
            p1 += __shfl_down(p1, 2, 4); p1 += __shfl_down(p1, 1, 4);
            if (part == 0) {
                p0 += bl[0];
                p1 += bl[1];
                if (flags[0]) {
                    unsigned int o = ((unsigned int)f2bf(p1) << 16) | (unsigned int)f2bf(p0);
                    ((unsigned int*)out_final)[row] = o;
                } else {
                    ((float2*)out_final)[row] = make_float2(p0, p1);
                }
            }
        }
    }
}

extern "C" void kernel_launch(void* const* d_in, const int* in_sizes, int n_in,
                              void* d_out, int out_size, void* d_ws, size_t ws_size,
                              hipStream_t stream) {
    const void* x_in = d_in[0];
    const int*  ei32 = (const int*)d_in[1];

    int N = in_sizes[0] / FEAT;
    int E = in_sizes[1] / 2;
    int NB = (N + 255) >> 8;
    int EC = (E + CHUNK - 1) / CHUNK;
    int HN = NB * EC;

    // workspace layout
    unsigned short* x16   = (unsigned short*)d_ws;                 // N*64 bf16
    unsigned short* h16   = x16 + (size_t)N * FEAT;                // N*64
    unsigned short* Wt    = h16 + (size_t)N * FEAT;                // 16384
    float*          wbuf  = (float*)(Wt + 16384);                  // 16704
    int*            hist  = (int*)(wbuf + 16704);                  // HN
    int*            hscan = hist + HN;                             // HN
    int*            bsum  = hscan + HN;                            // <=1024
    int*            flags = bsum + 1024;                           // 16
    int*            offs  = flags + 16;                            // N
    int*            cnt   = offs + N;                              // N
    int*            bkt   = cnt + N;                               // E
    int*            srcs  = bkt + E;                               // E

    float* b1_32 = wbuf + 8192;
    float* b2_32 = wbuf + 16448;
    float* wl32  = wbuf + 16512;
    float* bl32  = wbuf + 16640;

    // 0. prep + P1 merged (role-split grid)
    int n8 = N * FEAT / 8;
    int pBlocks = (n8 + 255) / 256;
    if (pBlocks < 66) pBlocks = 66;
    prep_p1_kernel<<<pBlocks + EC, 256, 0, stream>>>(
        (const unsigned short*)x_in, ei32,
        d_in[2], d_in[3], d_in[4], d_in[5], d_in[6], d_in[7], d_in[8], d_in[9],
        wbuf, Wt, flags, x_in, x16, n8,
        hist, E, N, NB, EC, pBlocks);

    // 1. scan -> scatter -> finalize
    int sB = (HN + 2047) / 2048;
    scan1_kernel<<<sB, 256, 0, stream>>>(hist, hscan, bsum, HN);
    scan3_kernel<<<sB, 256, 0, stream>>>(hscan, bsum, HN);
    p3_scatter_kernel<<<EC, 256, 0, stream>>>(ei32, hscan, bkt, E, N, NB, EC, flags);
    p4_build_kernel<<<NB, 256, 0, stream>>>(bkt, hscan, hist, offs, cnt, srcs, E, N, NB, EC);

    int gBlocks = (N + 63) / 64;

    // 2. layer 1: fused aggregate + GEMM (x -> h16)
    sage_fused_kernel<<<gBlocks, 256, 0, stream>>>(
        x_in, x16, srcs, offs, cnt, Wt, b1_32, h16, N,
        nullptr, nullptr, nullptr, flags, 1);

    // 3. layer 2: fused aggregate + GEMM + final projection
    sage_fused_kernel<<<gBlocks, 256, 0, stream>>>(
        h16, h16, srcs, offs, cnt, Wt + 8192, b2_32, nullptr, N,
        wl32, bl32, d_out, flags, 0);
}